// Round 9
// baseline (520.656 us; speedup 1.0000x reference)
//
#include <hip/hip_runtime.h>
#include <math.h>

#define EMB 64
#define MAXREL 32
#define BSHIFT 9            // bucket = 512 heads
#define BCAP 6912           // LDS record capacity per bucket (55296 B)
#define CH 2048             // edges per block in bucket_scatter

typedef short bf16x8 __attribute__((ext_vector_type(8)));
typedef float f32x4 __attribute__((ext_vector_type(4)));

__device__ __forceinline__ short f2bf(float f) {
    unsigned u = __float_as_uint(f);
    u += 0x7FFFu + ((u >> 16) & 1u);   // RNE
    return (short)(u >> 16);
}

#if __has_builtin(__builtin_amdgcn_cvt_pk_bf16_f32)
__device__ __forceinline__ short2 cvt2(float a, float b) {
    return __builtin_bit_cast(short2, __builtin_amdgcn_cvt_pk_bf16_f32(a, b));
}
#else
__device__ __forceinline__ short2 cvt2(float a, float b) {
    return make_short2(f2bf(a), f2bf(b));
}
#endif

// bf16 pair expansion from a packed dword (elem0 = low 16, elem1 = high 16)
__device__ __forceinline__ float lo_bf(unsigned d) { return __uint_as_float(d << 16); }
__device__ __forceinline__ float hi_bf(unsigned d) { return __uint_as_float(d & 0xffff0000u); }
__device__ __forceinline__ float bfs(short s) {
    return __uint_as_float(((unsigned)(unsigned short)s) << 16);
}

// A-fragment = bf16( bf16agg ⊙ rel_f32 )
__device__ __forceinline__ bf16x8 pack8bf(uint4 U, float4 r0, float4 r1) {
    short2 c0 = cvt2(lo_bf(U.x) * r0.x, hi_bf(U.x) * r0.y);
    short2 c1 = cvt2(lo_bf(U.y) * r0.z, hi_bf(U.y) * r0.w);
    short2 c2 = cvt2(lo_bf(U.z) * r1.x, hi_bf(U.z) * r1.y);
    short2 c3 = cvt2(lo_bf(U.w) * r1.z, hi_bf(U.w) * r1.w);
    bf16x8 a;
    a[0] = c0.x; a[1] = c0.y; a[2] = c1.x; a[3] = c1.y;
    a[4] = c2.x; a[5] = c2.y; a[6] = c3.x; a[7] = c3.y;
    return a;
}

__device__ __forceinline__ float fast_rcp(float x) {
#if __has_builtin(__builtin_amdgcn_rcpf)
    return __builtin_amdgcn_rcpf(x);
#else
    return 1.0f / x;
#endif
}

// fast tanh: 1 - 2/(e^{2|x|}+1), sign restored; v_rcp instead of full divide
__device__ __forceinline__ float fast_tanh(float x) {
    float ax = fabsf(x);
    float z = __expf(2.0f * ax);
    float r = 1.0f - 2.0f * fast_rcp(z + 1.0f);
    return copysignf(r, x);
}

// --- init: aggbf = bf16(entity_emb), kg(=d_out) = 0, deg = 0 (fused memset) ---
__global__ void init_kernel(short4* __restrict__ aggbf, float4* __restrict__ kg,
                            const float4* __restrict__ ent, int* __restrict__ deg,
                            int n4, int N) {
    int i = blockIdx.x * blockDim.x + threadIdx.x;
    if (i < n4) {
        float4 v = ent[i];
        short2 c0 = cvt2(v.x, v.y), c1 = cvt2(v.z, v.w);
        aggbf[i] = make_short4(c0.x, c0.y, c1.x, c1.y);
        kg[i] = make_float4(0.f, 0.f, 0.f, 0.f);
    }
    if (i < N) deg[i] = 0;
}

// ============ one-time CSR build (two-phase bucketed counting sort) ============

__global__ void hist_kernel(int* __restrict__ deg, const int* __restrict__ head, int E) {
    int e = blockIdx.x * blockDim.x + threadIdx.x;
    if (e < E) atomicAdd(&deg[head[e]], 1);
}

__global__ void scan_blocks(const int* __restrict__ deg, int* __restrict__ excl,
                            int* __restrict__ bsum, int n) {
    __shared__ int wsum[4];
    int base = blockIdx.x * 1024;
    int t = threadIdx.x;
    int lane = t & 63, wid = t >> 6;
    int idx = base + t * 4;
    int v0 = (idx + 0 < n) ? deg[idx + 0] : 0;
    int v1 = (idx + 1 < n) ? deg[idx + 1] : 0;
    int v2 = (idx + 2 < n) ? deg[idx + 2] : 0;
    int v3 = (idx + 3 < n) ? deg[idx + 3] : 0;
    int s0 = v0, s1 = s0 + v1, s2 = s1 + v2, s3 = s2 + v3;
    int tsum = s3;
    int inc = tsum;
#pragma unroll
    for (int o = 1; o < 64; o <<= 1) { int u = __shfl_up(inc, o, 64); if (lane >= o) inc += u; }
    if (lane == 63) wsum[wid] = inc;
    __syncthreads();
    int woff = 0;
#pragma unroll
    for (int w = 0; w < 4; ++w) if (w < wid) woff += wsum[w];
    int texcl = woff + inc - tsum;
    if (idx + 0 < n) excl[idx + 0] = texcl;
    if (idx + 1 < n) excl[idx + 1] = texcl + s0;
    if (idx + 2 < n) excl[idx + 2] = texcl + s1;
    if (idx + 3 < n) excl[idx + 3] = texcl + s2;
    if (t == 255) bsum[blockIdx.x] = woff + inc;
}

// parallel exclusive scan of block sums (nb <= 256 path; serial fallback otherwise)
__global__ void scan_sums(int* __restrict__ bsum, int* __restrict__ excl, int nb, int n, int E) {
    __shared__ int ws[4];
    int t = threadIdx.x;
    if (nb > 256) {
        if (t == 0) {
            int acc = 0;
            for (int b = 0; b < nb; ++b) { int v = bsum[b]; bsum[b] = acc; acc += v; }
            excl[n] = E;
        }
        return;
    }
    int lane = t & 63, wid = t >> 6;
    int v = (t < nb) ? bsum[t] : 0;
    int inc = v;
#pragma unroll
    for (int o = 1; o < 64; o <<= 1) { int u = __shfl_up(inc, o, 64); if (lane >= o) inc += u; }
    if (lane == 63) ws[wid] = inc;
    __syncthreads();
    int woff = 0;
#pragma unroll
    for (int w = 0; w < 4; ++w) if (w < wid) woff += ws[w];
    if (t < nb) bsum[t] = woff + inc - v;
    if (t == 0) excl[n] = E;
}

// finalize offsets AND seed bcursor[b] = offsets[b<<BSHIFT] (fused bucket_init)
__global__ void scan_add(int* __restrict__ excl, const int* __restrict__ bsum,
                         int* __restrict__ bcursor, int n) {
    int i = blockIdx.x * blockDim.x + threadIdx.x;
    if (i < n) {
        int v = excl[i] + bsum[i >> 10];
        excl[i] = v;
        if ((i & ((1 << BSHIFT) - 1)) == 0) bcursor[i >> BSHIFT] = v;
    }
}

// Phase A: partition edges into coarse buckets (head >> BSHIFT).
__global__ void bucket_scatter(const int* __restrict__ head, const int* __restrict__ tail,
                               const int* __restrict__ etype, int* __restrict__ bcursor,
                               int2* __restrict__ tmp, int E, int nb) {
    __shared__ int lcnt[512];
    __shared__ int lbase[512];
    int t = threadIdx.x;
    int base = blockIdx.x * CH;
    for (int i = t; i < 512; i += 256) lcnt[i] = 0;
    __syncthreads();
    int myh[8];
#pragma unroll
    for (int i = 0; i < 8; ++i) {
        int e = base + i * 256 + t;
        if (e < E) {
            int h = head[e];
            myh[i] = h;
            atomicAdd(&lcnt[h >> BSHIFT], 1);
        } else myh[i] = -1;
    }
    __syncthreads();
    for (int b = t; b < nb; b += 256) {
        int c = lcnt[b];
        lbase[b] = (c > 0) ? atomicAdd(&bcursor[b], c) : 0;
        lcnt[b] = 0;
    }
    __syncthreads();
#pragma unroll
    for (int i = 0; i < 8; ++i) {
        int e = base + i * 256 + t;
        if (e < E) {
            int h = myh[i];
            int b = h >> BSHIFT;
            int pos = lbase[b] + atomicAdd(&lcnt[b], 1);
            tmp[pos] = make_int2(h, tail[e] | (etype[e] << 20));
        }
    }
}

// Phase B: per-bucket counting sort fully in LDS.
__global__ void bucket_sort(const int* __restrict__ offsets, const int2* __restrict__ tmp,
                            int2* __restrict__ spair, int N) {
    __shared__ int2 staged[BCAP];
    __shared__ int lcur[1 << BSHIFT];
    int b = blockIdx.x;
    int h0 = b << BSHIFT;
    int h1 = min(h0 + (1 << BSHIFT), N);
    int r0 = offsets[h0], r1 = offsets[h1];
    int cnt = r1 - r0;
    int t = threadIdx.x;
    for (int h = h0 + t; h < h1; h += blockDim.x) lcur[h - h0] = offsets[h] - r0;
    __syncthreads();
    if (cnt <= BCAP) {
        for (int i = t; i < cnt; i += blockDim.x) {
            int2 rec = tmp[r0 + i];
            int lp = atomicAdd(&lcur[rec.x - h0], 1);
            staged[lp] = rec;
        }
        __syncthreads();
        for (int i = t; i < cnt; i += blockDim.x) spair[r0 + i] = staged[i];
    } else {
        for (int i = t; i < cnt; i += blockDim.x) {
            int2 rec = tmp[r0 + i];
            int lp = atomicAdd(&lcur[rec.x - h0], 1);
            spair[r0 + lp] = rec;
        }
    }
}

// ============ per-hop kernels ============

__device__ __forceinline__ void build_bfrags(bf16x8 bfrag[2][4], const float* __restrict__ W,
                                             int lane) {
    int koff = (lane >> 4) * 8;
    int n = lane & 15;
#pragma unroll
    for (int kh = 0; kh < 2; ++kh)
#pragma unroll
        for (int nt = 0; nt < 4; ++nt) {
            bf16x8 b;
#pragma unroll
            for (int j = 0; j < 8; ++j)
                b[j] = f2bf(W[(kh * 32 + koff + j) * EMB + nt * 16 + n]);
            bfrag[kh][nt] = b;
        }
}

// --- Q = agg @ q_w via MFMA: bf16 in, bf16 out ---
__global__ __launch_bounds__(256, 4) void qproj_mfma_kernel(
        short* __restrict__ Qbf, const short* __restrict__ aggbf,
        const float* __restrict__ qw, int N) {
    int lane = threadIdx.x & 63;
    int gwave = blockIdx.x * (blockDim.x >> 6) + (threadIdx.x >> 6);
    int nwaves = gridDim.x * (blockDim.x >> 6);
    int row = lane & 15;
    int g = lane >> 4;
    int koff = g * 8;

    bf16x8 bfrag[2][4];
    build_bfrags(bfrag, qw, lane);

    int ntiles = (N + 15) >> 4;
    for (int tile = gwave; tile < ntiles; tile += nwaves) {
        int rIdx = min(tile * 16 + row, N - 1);
        const short* rowp = aggbf + (size_t)rIdx * EMB;
        bf16x8 a0 = *(const bf16x8*)(rowp + koff);
        bf16x8 a1 = *(const bf16x8*)(rowp + 32 + koff);
#pragma unroll
        for (int nt = 0; nt < 4; ++nt) {
            f32x4 acc = {0.f, 0.f, 0.f, 0.f};
            acc = __builtin_amdgcn_mfma_f32_16x16x32_bf16(a0, bfrag[0][nt], acc, 0, 0, 0);
            acc = __builtin_amdgcn_mfma_f32_16x16x32_bf16(a1, bfrag[1][nt], acc, 0, 0, 0);
#pragma unroll
            for (int reg = 0; reg < 4; ++reg) {
                int n2 = tile * 16 + g * 4 + reg;
                if (n2 < N) Qbf[(size_t)n2 * EMB + nt * 16 + (lane & 15)] = f2bf(acc[reg]);
            }
        }
    }
}

// --- per-edge attention via MFMA over SORTED packed edges; 1-deep prefetch
//     (round-5 proven form; round-7's 2-deep queue spilled to scratch: +27 MB
//     WRITE_SIZE). __launch_bounds__(256,8): 52 VGPR fits the 64-reg/8-wave
//     budget -- guarantee full occupancy for latency hiding. ---
__global__ __launch_bounds__(256, 8) void att_mfma_kernel(
        float* __restrict__ att,
        const short* __restrict__ aggbf, const short* __restrict__ Qbf,
        const float* __restrict__ eemb, const float* __restrict__ kw,
        const int2* __restrict__ spair, int E) {
    int lane = threadIdx.x & 63;
    int gwave = blockIdx.x * (blockDim.x >> 6) + (threadIdx.x >> 6);
    int nwaves = gridDim.x * (blockDim.x >> 6);
    int row = lane & 15;
    int g = lane >> 4;

    bf16x8 bfrag[2][4];
    build_bfrags(bfrag, kw, lane);

    int ntiles = (E + 15) >> 4;
    int tile = gwave;
    int2 pr = make_int2(0, 0);
    uint4 U0 = make_uint4(0, 0, 0, 0), U1 = make_uint4(0, 0, 0, 0);
    if (tile < ntiles) {
        pr = spair[min(tile * 16 + row, E - 1)];
        const uint4* rowa = (const uint4*)(aggbf + (size_t)(pr.y & 0xFFFFF) * EMB);
        U0 = rowa[g];
        U1 = rowa[4 + g];
    }
    for (; tile < ntiles; tile += nwaves) {
        int tnext = tile + nwaves;
        // prefetch next tile's edge record early (independent of current compute)
        int2 prn = pr;
        if (tnext < ntiles) prn = spair[min(tnext * 16 + row, E - 1)];

        int h = pr.x;
        unsigned r = ((unsigned)pr.y) >> 20;
        const float4* rl4 = (const float4*)(eemb + (size_t)r * EMB);
        float4 y0 = rl4[g * 2], y1 = rl4[g * 2 + 1];
        float4 y2 = rl4[8 + g * 2], y3 = rl4[8 + g * 2 + 1];
        bf16x8 a0 = pack8bf(U0, y0, y1);
        bf16x8 a1 = pack8bf(U1, y2, y3);

        // prefetch next tile's agg rows (latency hides under MFMA/tanh phase)
        uint4 U0n = U0, U1n = U1;
        if (tnext < ntiles) {
            const uint4* rowan = (const uint4*)(aggbf + (size_t)(prn.y & 0xFFFFF) * EMB);
            U0n = rowan[g];
            U1n = rowan[4 + g];
        }

        // hoist head broadcasts (invariant over nt) + Q row pointers
        int h2r0 = __shfl(h, g * 4 + 0, 64);
        int h2r1 = __shfl(h, g * 4 + 1, 64);
        int h2r2 = __shfl(h, g * 4 + 2, 64);
        int h2r3 = __shfl(h, g * 4 + 3, 64);
        const short* q0 = Qbf + (size_t)h2r0 * EMB + row;
        const short* q1 = Qbf + (size_t)h2r1 * EMB + row;
        const short* q2 = Qbf + (size_t)h2r2 * EMB + row;
        const short* q3 = Qbf + (size_t)h2r3 * EMB + row;

        float sums0 = 0.f, sums1 = 0.f, sums2 = 0.f, sums3 = 0.f;
#pragma unroll
        for (int nt = 0; nt < 4; ++nt) {
            f32x4 acc = {0.f, 0.f, 0.f, 0.f};
            acc = __builtin_amdgcn_mfma_f32_16x16x32_bf16(a0, bfrag[0][nt], acc, 0, 0, 0);
            acc = __builtin_amdgcn_mfma_f32_16x16x32_bf16(a1, bfrag[1][nt], acc, 0, 0, 0);
            sums0 += bfs(q0[nt * 16]) * fast_tanh(acc[0]);
            sums1 += bfs(q1[nt * 16]) * fast_tanh(acc[1]);
            sums2 += bfs(q2[nt * 16]) * fast_tanh(acc[2]);
            sums3 += bfs(q3[nt * 16]) * fast_tanh(acc[3]);
        }
#pragma unroll
        for (int m = 1; m <= 8; m <<= 1) {
            sums0 += __shfl_xor(sums0, m, 64);
            sums1 += __shfl_xor(sums1, m, 64);
            sums2 += __shfl_xor(sums2, m, 64);
            sums3 += __shfl_xor(sums3, m, 64);
        }
#pragma unroll
        for (int reg = 0; reg < 4; ++reg) {
            int row2 = g * 4 + reg;
            int e2 = tile * 16 + row2;
            float v = (reg == 0) ? sums0 : (reg == 1) ? sums1 : (reg == 2) ? sums2 : sums3;
            if (row == reg && e2 < E) att[e2] = v;
        }
        pr = prn; U0 = U0n; U1 = U1n;
    }
}

// --- fused per-head softmax+aggregate: QUARTER-WAVE per head.
//     Fast path for deg<=16; general chunked path with quad-unroll otherwise. ---
__global__ __launch_bounds__(256, 4) void head_agg_kernel(
        short* __restrict__ aggNewBf, float* __restrict__ kg,
        const float* __restrict__ att, const short* __restrict__ aggOldBf,
        const float* __restrict__ eemb, const float* __restrict__ ent,
        const int* __restrict__ offsets, const int2* __restrict__ spair,
        int N, int R) {
    __shared__ float4 elds4[MAXREL * 16];

    int tid = threadIdx.x;
    int lane = tid & 63;
    int wid = tid >> 6;
    int RS = (R < MAXREL) ? R : MAXREL;
    for (int i = tid; i < RS * 16; i += blockDim.x) elds4[i] = ((const float4*)eemb)[i];
    __syncthreads();

    int sub = lane >> 4;     // quarter index = which head of this wave
    int q = lane & 15;       // dim quad within the head
    int h = (blockIdx.x * (blockDim.x >> 6) + wid) * 4 + sub;
    if (h >= N) return;
    int beg = offsets[h], end = offsets[h + 1];
    int deg = end - beg;
    int qbase = lane & 48;

    float4 acc4 = make_float4(0.f, 0.f, 0.f, 0.f);
    float ssum = 0.f;

    auto body = [&](float ej, int trj) {
        int tj = trj & 0xFFFFF;
        unsigned rj = ((unsigned)trj) >> 20;
        float4 ew = (rj < (unsigned)RS) ? elds4[rj * 16 + q]
                                        : ((const float4*)eemb)[(size_t)rj * 16 + q];
        uint2 X = ((const uint2*)(aggOldBf + (size_t)tj * EMB))[q];
        acc4.x += ej * ew.x * lo_bf(X.x);
        acc4.y += ej * ew.y * hi_bf(X.x);
        acc4.z += ej * ew.z * lo_bf(X.y);
        acc4.w += ej * ew.w * hi_bf(X.y);
    };

    if (deg <= 16) {
        // ---- single-chunk fast path ----
        int e = beg + q;
        bool valid = q < deg;
        float av = valid ? att[e] : -3.4e38f;
        int tr = valid ? spair[e].y : 0;
        float m = av;
#pragma unroll
        for (int o = 1; o <= 8; o <<= 1) m = fmaxf(m, __shfl_xor(m, o, 64));
        float ev = valid ? __expf(av - m) : 0.f;
        ssum = ev;
        auto B = [&](int j) { body(__shfl(ev, qbase | j, 64), __shfl(tr, qbase | j, 64)); };
        int j = 0;
        for (; j + 4 <= deg; j += 4) { B(j); B(j + 1); B(j + 2); B(j + 3); }
        for (; j < deg; ++j) B(j);
    } else {
        // ---- general chunked path ----
        float m = -3.4e38f;
        for (int e = beg + q; e < end; e += 16) m = fmaxf(m, att[e]);
#pragma unroll
        for (int o = 1; o <= 8; o <<= 1) m = fmaxf(m, __shfl_xor(m, o, 64));

        for (int c = beg; c < end; c += 16) {
            int e = c + q;
            float ev = 0.f; int tr = 0;
            if (e < end) {
                ev = __expf(att[e] - m);
                tr = spair[e].y;
            }
            ssum += ev;
            int nc = min(16, end - c);
            auto B = [&](int j) { body(__shfl(ev, qbase | j, 64), __shfl(tr, qbase | j, 64)); };
            if (nc == 16) {
#pragma unroll 4
                for (int j = 0; j < 16; ++j) B(j);
            } else {
                int j = 0;
                for (; j + 4 <= nc; j += 4) { B(j); B(j + 1); B(j + 2); B(j + 3); }
                for (; j < nc; ++j) B(j);
            }
        }
    }
#pragma unroll
    for (int o = 1; o <= 8; o <<= 1) ssum += __shfl_xor(ssum, o, 64);

    float scale = (deg > 0) ? 1.0f / (ssum * (float)deg) : 0.f;
    float4 v = make_float4(acc4.x * scale, acc4.y * scale, acc4.z * scale, acc4.w * scale);
    float ss = v.x * v.x + v.y * v.y + v.z * v.z + v.w * v.w;
#pragma unroll
    for (int o = 1; o <= 8; o <<= 1) ss += __shfl_xor(ss, o, 64);
    float rinv = 1.0f / fmaxf(sqrtf(ss), 1e-12f);
    v.x *= rinv; v.y *= rinv; v.z *= rinv; v.w *= rinv;

    short2 c0 = cvt2(v.x, v.y), c1 = cvt2(v.z, v.w);
    ((short4*)aggNewBf)[(size_t)h * 16 + q] = make_short4(c0.x, c0.y, c1.x, c1.y);
    float4 kgv = ((float4*)kg)[(size_t)h * 16 + q];
    float4 ev2 = ((const float4*)ent)[(size_t)h * 16 + q];
    kgv.x += v.x + ev2.x; kgv.y += v.y + ev2.y;
    kgv.z += v.z + ev2.z; kgv.w += v.w + ev2.w;
    ((float4*)kg)[(size_t)h * 16 + q] = kgv;
}

extern "C" void kernel_launch(void* const* d_in, const int* in_sizes, int n_in,
                              void* d_out, int out_size, void* d_ws, size_t ws_size,
                              hipStream_t stream) {
    const float* ent  = (const float*)d_in[0];
    const float* eemb = (const float*)d_in[1];
    const float* qw   = (const float*)d_in[2];
    const float* kw   = (const float*)d_in[3];
    const int* eidx  = (const int*)d_in[4];
    const int* etype = (const int*)d_in[5];

    const int N = in_sizes[0] / EMB;
    const int R = in_sizes[1] / EMB;
    const int E = in_sizes[5];
    const int* head = eidx;
    const int* tail = eidx + E;

    float* kg = (float*)d_out;

    // workspace layout
    float* att   = (float*)d_ws;                 // E f32
    int2* spair  = (int2*)(att + E);             // E int2
    int* offsets = (int*)(spair + E);            // N+1
    int* deg     = offsets + (N + 1);            // N
    int* bcursor = deg + N;                      // N (only nbk used)
    int* bsum    = bcursor + N;                  // 1024
    uintptr_t pa = ((uintptr_t)(bsum + 1024) + 15) & ~(uintptr_t)15;
    short* aggbf_a = (short*)pa;                 // N*EMB bf16 (16-B aligned)
    short* aggbf_b = aggbf_a + (size_t)N * EMB;  // N*EMB bf16
    short* Qbf     = aggbf_b + (size_t)N * EMB;  // N*EMB bf16
    int2* tmp      = (int2*)Qbf;                 // E int2, aliases Qbf (pre-hop only)

    const int NT = 256;
    const int nb = (N + 1023) / 1024;
    const int nbk = (N + (1 << BSHIFT) - 1) >> BSHIFT;

    init_kernel<<<(N * EMB / 4 + NT - 1) / NT, NT, 0, stream>>>(
        (short4*)aggbf_a, (float4*)kg, (const float4*)ent, deg, N * EMB / 4, N);
    hist_kernel<<<(E + NT - 1) / NT, NT, 0, stream>>>(deg, head, E);
    scan_blocks<<<nb, NT, 0, stream>>>(deg, offsets, bsum, N);
    scan_sums<<<1, NT, 0, stream>>>(bsum, offsets, nb, N, E);
    scan_add<<<(N + NT - 1) / NT, NT, 0, stream>>>(offsets, bsum, bcursor, N);
    bucket_scatter<<<(E + CH - 1) / CH, NT, 0, stream>>>(head, tail, etype, bcursor, tmp, E, nbk);
    bucket_sort<<<nbk, NT, 0, stream>>>(offsets, tmp, spair, N);

    short* curbf = aggbf_a;
    short* nxtbf = aggbf_b;
    for (int hop = 0; hop < 2; ++hop) {
        qproj_mfma_kernel<<<512, NT, 0, stream>>>(Qbf, curbf, qw, N);
        att_mfma_kernel<<<2048, NT, 0, stream>>>(att, curbf, Qbf, eemb, kw, spair, E);
        // 4 waves/block x 4 heads/wave = 16 heads/block
        head_agg_kernel<<<(N + 15) / 16, NT, 0, stream>>>(nxtbf, kg, att, curbf,
                                                          eemb, ent, offsets, spair, N, R);
        short* ts = curbf; curbf = nxtbf; nxtbf = ts;
    }
}

// Round 10
// 407.315 us; speedup vs baseline: 1.2783x; 1.2783x over previous
//
#include <hip/hip_runtime.h>
#include <math.h>

#define EMB 64
#define MAXREL 32
#define BSHIFT 9            // bucket = 512 heads
#define BCAP 6912           // LDS record capacity per bucket (55296 B)
#define CH 2048             // edges per block in bucket_scatter

typedef short bf16x8 __attribute__((ext_vector_type(8)));
typedef float f32x4 __attribute__((ext_vector_type(4)));

__device__ __forceinline__ short f2bf(float f) {
    unsigned u = __float_as_uint(f);
    u += 0x7FFFu + ((u >> 16) & 1u);   // RNE
    return (short)(u >> 16);
}

#if __has_builtin(__builtin_amdgcn_cvt_pk_bf16_f32)
__device__ __forceinline__ short2 cvt2(float a, float b) {
    return __builtin_bit_cast(short2, __builtin_amdgcn_cvt_pk_bf16_f32(a, b));
}
#else
__device__ __forceinline__ short2 cvt2(float a, float b) {
    return make_short2(f2bf(a), f2bf(b));
}
#endif

// bf16 pair expansion from a packed dword (elem0 = low 16, elem1 = high 16)
__device__ __forceinline__ float lo_bf(unsigned d) { return __uint_as_float(d << 16); }
__device__ __forceinline__ float hi_bf(unsigned d) { return __uint_as_float(d & 0xffff0000u); }
__device__ __forceinline__ float bfs(short s) {
    return __uint_as_float(((unsigned)(unsigned short)s) << 16);
}

// A-fragment = bf16( bf16agg ⊙ rel_f32 )
__device__ __forceinline__ bf16x8 pack8bf(uint4 U, float4 r0, float4 r1) {
    short2 c0 = cvt2(lo_bf(U.x) * r0.x, hi_bf(U.x) * r0.y);
    short2 c1 = cvt2(lo_bf(U.y) * r0.z, hi_bf(U.y) * r0.w);
    short2 c2 = cvt2(lo_bf(U.z) * r1.x, hi_bf(U.z) * r1.y);
    short2 c3 = cvt2(lo_bf(U.w) * r1.z, hi_bf(U.w) * r1.w);
    bf16x8 a;
    a[0] = c0.x; a[1] = c0.y; a[2] = c1.x; a[3] = c1.y;
    a[4] = c2.x; a[5] = c2.y; a[6] = c3.x; a[7] = c3.y;
    return a;
}

__device__ __forceinline__ float fast_rcp(float x) {
#if __has_builtin(__builtin_amdgcn_rcpf)
    return __builtin_amdgcn_rcpf(x);
#else
    return 1.0f / x;
#endif
}

// fast tanh: 1 - 2/(e^{2|x|}+1), sign restored; v_rcp instead of full divide
__device__ __forceinline__ float fast_tanh(float x) {
    float ax = fabsf(x);
    float z = __expf(2.0f * ax);
    float r = 1.0f - 2.0f * fast_rcp(z + 1.0f);
    return copysignf(r, x);
}

// --- init: aggbf = bf16(entity_emb), kg(=d_out) = 0, deg = 0 (fused memset) ---
__global__ void init_kernel(short4* __restrict__ aggbf, float4* __restrict__ kg,
                            const float4* __restrict__ ent, int* __restrict__ deg,
                            int n4, int N) {
    int i = blockIdx.x * blockDim.x + threadIdx.x;
    if (i < n4) {
        float4 v = ent[i];
        short2 c0 = cvt2(v.x, v.y), c1 = cvt2(v.z, v.w);
        aggbf[i] = make_short4(c0.x, c0.y, c1.x, c1.y);
        kg[i] = make_float4(0.f, 0.f, 0.f, 0.f);
    }
    if (i < N) deg[i] = 0;
}

// ============ one-time CSR build (two-phase bucketed counting sort) ============

__global__ void hist_kernel(int* __restrict__ deg, const int* __restrict__ head, int E) {
    int e = blockIdx.x * blockDim.x + threadIdx.x;
    if (e < E) atomicAdd(&deg[head[e]], 1);
}

__global__ void scan_blocks(const int* __restrict__ deg, int* __restrict__ excl,
                            int* __restrict__ bsum, int n) {
    __shared__ int wsum[4];
    int base = blockIdx.x * 1024;
    int t = threadIdx.x;
    int lane = t & 63, wid = t >> 6;
    int idx = base + t * 4;
    int v0 = (idx + 0 < n) ? deg[idx + 0] : 0;
    int v1 = (idx + 1 < n) ? deg[idx + 1] : 0;
    int v2 = (idx + 2 < n) ? deg[idx + 2] : 0;
    int v3 = (idx + 3 < n) ? deg[idx + 3] : 0;
    int s0 = v0, s1 = s0 + v1, s2 = s1 + v2, s3 = s2 + v3;
    int tsum = s3;
    int inc = tsum;
#pragma unroll
    for (int o = 1; o < 64; o <<= 1) { int u = __shfl_up(inc, o, 64); if (lane >= o) inc += u; }
    if (lane == 63) wsum[wid] = inc;
    __syncthreads();
    int woff = 0;
#pragma unroll
    for (int w = 0; w < 4; ++w) if (w < wid) woff += wsum[w];
    int texcl = woff + inc - tsum;
    if (idx + 0 < n) excl[idx + 0] = texcl;
    if (idx + 1 < n) excl[idx + 1] = texcl + s0;
    if (idx + 2 < n) excl[idx + 2] = texcl + s1;
    if (idx + 3 < n) excl[idx + 3] = texcl + s2;
    if (t == 255) bsum[blockIdx.x] = woff + inc;
}

// parallel exclusive scan of block sums (nb <= 256 path; serial fallback otherwise)
__global__ void scan_sums(int* __restrict__ bsum, int* __restrict__ excl, int nb, int n, int E) {
    __shared__ int ws[4];
    int t = threadIdx.x;
    if (nb > 256) {
        if (t == 0) {
            int acc = 0;
            for (int b = 0; b < nb; ++b) { int v = bsum[b]; bsum[b] = acc; acc += v; }
            excl[n] = E;
        }
        return;
    }
    int lane = t & 63, wid = t >> 6;
    int v = (t < nb) ? bsum[t] : 0;
    int inc = v;
#pragma unroll
    for (int o = 1; o < 64; o <<= 1) { int u = __shfl_up(inc, o, 64); if (lane >= o) inc += u; }
    if (lane == 63) ws[wid] = inc;
    __syncthreads();
    int woff = 0;
#pragma unroll
    for (int w = 0; w < 4; ++w) if (w < wid) woff += ws[w];
    if (t < nb) bsum[t] = woff + inc - v;
    if (t == 0) excl[n] = E;
}

// finalize offsets AND seed bcursor[b] = offsets[b<<BSHIFT] (fused bucket_init)
__global__ void scan_add(int* __restrict__ excl, const int* __restrict__ bsum,
                         int* __restrict__ bcursor, int n) {
    int i = blockIdx.x * blockDim.x + threadIdx.x;
    if (i < n) {
        int v = excl[i] + bsum[i >> 10];
        excl[i] = v;
        if ((i & ((1 << BSHIFT) - 1)) == 0) bcursor[i >> BSHIFT] = v;
    }
}

// Phase A: partition edges into coarse buckets (head >> BSHIFT).
__global__ void bucket_scatter(const int* __restrict__ head, const int* __restrict__ tail,
                               const int* __restrict__ etype, int* __restrict__ bcursor,
                               int2* __restrict__ tmp, int E, int nb) {
    __shared__ int lcnt[512];
    __shared__ int lbase[512];
    int t = threadIdx.x;
    int base = blockIdx.x * CH;
    for (int i = t; i < 512; i += 256) lcnt[i] = 0;
    __syncthreads();
    int myh[8];
#pragma unroll
    for (int i = 0; i < 8; ++i) {
        int e = base + i * 256 + t;
        if (e < E) {
            int h = head[e];
            myh[i] = h;
            atomicAdd(&lcnt[h >> BSHIFT], 1);
        } else myh[i] = -1;
    }
    __syncthreads();
    for (int b = t; b < nb; b += 256) {
        int c = lcnt[b];
        lbase[b] = (c > 0) ? atomicAdd(&bcursor[b], c) : 0;
        lcnt[b] = 0;
    }
    __syncthreads();
#pragma unroll
    for (int i = 0; i < 8; ++i) {
        int e = base + i * 256 + t;
        if (e < E) {
            int h = myh[i];
            int b = h >> BSHIFT;
            int pos = lbase[b] + atomicAdd(&lcnt[b], 1);
            tmp[pos] = make_int2(h, tail[e] | (etype[e] << 20));
        }
    }
}

// Phase B: per-bucket counting sort fully in LDS.
__global__ void bucket_sort(const int* __restrict__ offsets, const int2* __restrict__ tmp,
                            int2* __restrict__ spair, int N) {
    __shared__ int2 staged[BCAP];
    __shared__ int lcur[1 << BSHIFT];
    int b = blockIdx.x;
    int h0 = b << BSHIFT;
    int h1 = min(h0 + (1 << BSHIFT), N);
    int r0 = offsets[h0], r1 = offsets[h1];
    int cnt = r1 - r0;
    int t = threadIdx.x;
    for (int h = h0 + t; h < h1; h += blockDim.x) lcur[h - h0] = offsets[h] - r0;
    __syncthreads();
    if (cnt <= BCAP) {
        for (int i = t; i < cnt; i += blockDim.x) {
            int2 rec = tmp[r0 + i];
            int lp = atomicAdd(&lcur[rec.x - h0], 1);
            staged[lp] = rec;
        }
        __syncthreads();
        for (int i = t; i < cnt; i += blockDim.x) spair[r0 + i] = staged[i];
    } else {
        for (int i = t; i < cnt; i += blockDim.x) {
            int2 rec = tmp[r0 + i];
            int lp = atomicAdd(&lcur[rec.x - h0], 1);
            spair[r0 + lp] = rec;
        }
    }
}

// ============ per-hop kernels ============

__device__ __forceinline__ void build_bfrags(bf16x8 bfrag[2][4], const float* __restrict__ W,
                                             int lane) {
    int koff = (lane >> 4) * 8;
    int n = lane & 15;
#pragma unroll
    for (int kh = 0; kh < 2; ++kh)
#pragma unroll
        for (int nt = 0; nt < 4; ++nt) {
            bf16x8 b;
#pragma unroll
            for (int j = 0; j < 8; ++j)
                b[j] = f2bf(W[(kh * 32 + koff + j) * EMB + nt * 16 + n]);
            bfrag[kh][nt] = b;
        }
}

// --- Q = agg @ q_w via MFMA: bf16 in, bf16 out ---
__global__ void qproj_mfma_kernel(short* __restrict__ Qbf, const short* __restrict__ aggbf,
                                  const float* __restrict__ qw, int N) {
    int lane = threadIdx.x & 63;
    int gwave = blockIdx.x * (blockDim.x >> 6) + (threadIdx.x >> 6);
    int nwaves = gridDim.x * (blockDim.x >> 6);
    int row = lane & 15;
    int g = lane >> 4;
    int koff = g * 8;

    bf16x8 bfrag[2][4];
    build_bfrags(bfrag, qw, lane);

    int ntiles = (N + 15) >> 4;
    for (int tile = gwave; tile < ntiles; tile += nwaves) {
        int rIdx = min(tile * 16 + row, N - 1);
        const short* rowp = aggbf + (size_t)rIdx * EMB;
        bf16x8 a0 = *(const bf16x8*)(rowp + koff);
        bf16x8 a1 = *(const bf16x8*)(rowp + 32 + koff);
#pragma unroll
        for (int nt = 0; nt < 4; ++nt) {
            f32x4 acc = {0.f, 0.f, 0.f, 0.f};
            acc = __builtin_amdgcn_mfma_f32_16x16x32_bf16(a0, bfrag[0][nt], acc, 0, 0, 0);
            acc = __builtin_amdgcn_mfma_f32_16x16x32_bf16(a1, bfrag[1][nt], acc, 0, 0, 0);
#pragma unroll
            for (int reg = 0; reg < 4; ++reg) {
                int n2 = tile * 16 + g * 4 + reg;
                if (n2 < N) Qbf[(size_t)n2 * EMB + nt * 16 + (lane & 15)] = f2bf(acc[reg]);
            }
        }
    }
}

// --- per-edge attention via MFMA over SORTED packed edges; 1-deep prefetch.
//     NO launch_bounds: round-9 proved forcing 8 waves/EU (VGPR 32) spills
//     (+57 MB scratch writes) AND triples L2 miss traffic (FETCH 103->323 MB).
//     VGPR 52 @ ~40% occupancy is the measured balanced point. ---
__global__ void att_mfma_kernel(float* __restrict__ att,
                                const short* __restrict__ aggbf, const short* __restrict__ Qbf,
                                const float* __restrict__ eemb, const float* __restrict__ kw,
                                const int2* __restrict__ spair, int E) {
    int lane = threadIdx.x & 63;
    int gwave = blockIdx.x * (blockDim.x >> 6) + (threadIdx.x >> 6);
    int nwaves = gridDim.x * (blockDim.x >> 6);
    int row = lane & 15;
    int g = lane >> 4;

    bf16x8 bfrag[2][4];
    build_bfrags(bfrag, kw, lane);

    int ntiles = (E + 15) >> 4;
    int tile = gwave;
    int2 pr = make_int2(0, 0);
    uint4 U0 = make_uint4(0, 0, 0, 0), U1 = make_uint4(0, 0, 0, 0);
    if (tile < ntiles) {
        pr = spair[min(tile * 16 + row, E - 1)];
        const uint4* rowa = (const uint4*)(aggbf + (size_t)(pr.y & 0xFFFFF) * EMB);
        U0 = rowa[g];
        U1 = rowa[4 + g];
    }
    for (; tile < ntiles; tile += nwaves) {
        int tnext = tile + nwaves;
        // prefetch next tile's edge record early (independent of current compute)
        int2 prn = pr;
        if (tnext < ntiles) prn = spair[min(tnext * 16 + row, E - 1)];

        int h = pr.x;
        unsigned r = ((unsigned)pr.y) >> 20;
        const float4* rl4 = (const float4*)(eemb + (size_t)r * EMB);
        float4 y0 = rl4[g * 2], y1 = rl4[g * 2 + 1];
        float4 y2 = rl4[8 + g * 2], y3 = rl4[8 + g * 2 + 1];
        bf16x8 a0 = pack8bf(U0, y0, y1);
        bf16x8 a1 = pack8bf(U1, y2, y3);

        // prefetch next tile's agg rows (latency hides under MFMA/tanh phase)
        uint4 U0n = U0, U1n = U1;
        if (tnext < ntiles) {
            const uint4* rowan = (const uint4*)(aggbf + (size_t)(prn.y & 0xFFFFF) * EMB);
            U0n = rowan[g];
            U1n = rowan[4 + g];
        }

        // hoist head broadcasts (invariant over nt) + Q row pointers
        int h2r0 = __shfl(h, g * 4 + 0, 64);
        int h2r1 = __shfl(h, g * 4 + 1, 64);
        int h2r2 = __shfl(h, g * 4 + 2, 64);
        int h2r3 = __shfl(h, g * 4 + 3, 64);
        const short* q0 = Qbf + (size_t)h2r0 * EMB + row;
        const short* q1 = Qbf + (size_t)h2r1 * EMB + row;
        const short* q2 = Qbf + (size_t)h2r2 * EMB + row;
        const short* q3 = Qbf + (size_t)h2r3 * EMB + row;

        float sums0 = 0.f, sums1 = 0.f, sums2 = 0.f, sums3 = 0.f;
#pragma unroll
        for (int nt = 0; nt < 4; ++nt) {
            f32x4 acc = {0.f, 0.f, 0.f, 0.f};
            acc = __builtin_amdgcn_mfma_f32_16x16x32_bf16(a0, bfrag[0][nt], acc, 0, 0, 0);
            acc = __builtin_amdgcn_mfma_f32_16x16x32_bf16(a1, bfrag[1][nt], acc, 0, 0, 0);
            sums0 += bfs(q0[nt * 16]) * fast_tanh(acc[0]);
            sums1 += bfs(q1[nt * 16]) * fast_tanh(acc[1]);
            sums2 += bfs(q2[nt * 16]) * fast_tanh(acc[2]);
            sums3 += bfs(q3[nt * 16]) * fast_tanh(acc[3]);
        }
#pragma unroll
        for (int m = 1; m <= 8; m <<= 1) {
            sums0 += __shfl_xor(sums0, m, 64);
            sums1 += __shfl_xor(sums1, m, 64);
            sums2 += __shfl_xor(sums2, m, 64);
            sums3 += __shfl_xor(sums3, m, 64);
        }
#pragma unroll
        for (int reg = 0; reg < 4; ++reg) {
            int row2 = g * 4 + reg;
            int e2 = tile * 16 + row2;
            float v = (reg == 0) ? sums0 : (reg == 1) ? sums1 : (reg == 2) ? sums2 : sums3;
            if (row == reg && e2 < E) att[e2] = v;
        }
        pr = prn; U0 = U0n; U1 = U1n;
    }
}

// --- fused per-head softmax+aggregate: QUARTER-WAVE per head.
//     Fast path for deg<=16; general chunked path with quad-unroll otherwise. ---
__global__ void head_agg_kernel(short* __restrict__ aggNewBf, float* __restrict__ kg,
                                const float* __restrict__ att, const short* __restrict__ aggOldBf,
                                const float* __restrict__ eemb, const float* __restrict__ ent,
                                const int* __restrict__ offsets, const int2* __restrict__ spair,
                                int N, int R) {
    __shared__ float4 elds4[MAXREL * 16];

    int tid = threadIdx.x;
    int lane = tid & 63;
    int wid = tid >> 6;
    int RS = (R < MAXREL) ? R : MAXREL;
    for (int i = tid; i < RS * 16; i += blockDim.x) elds4[i] = ((const float4*)eemb)[i];
    __syncthreads();

    int sub = lane >> 4;     // quarter index = which head of this wave
    int q = lane & 15;       // dim quad within the head
    int h = (blockIdx.x * (blockDim.x >> 6) + wid) * 4 + sub;
    if (h >= N) return;
    int beg = offsets[h], end = offsets[h + 1];
    int deg = end - beg;
    int qbase = lane & 48;

    float4 acc4 = make_float4(0.f, 0.f, 0.f, 0.f);
    float ssum = 0.f;

    auto body = [&](float ej, int trj) {
        int tj = trj & 0xFFFFF;
        unsigned rj = ((unsigned)trj) >> 20;
        float4 ew = (rj < (unsigned)RS) ? elds4[rj * 16 + q]
                                        : ((const float4*)eemb)[(size_t)rj * 16 + q];
        uint2 X = ((const uint2*)(aggOldBf + (size_t)tj * EMB))[q];
        acc4.x += ej * ew.x * lo_bf(X.x);
        acc4.y += ej * ew.y * hi_bf(X.x);
        acc4.z += ej * ew.z * lo_bf(X.y);
        acc4.w += ej * ew.w * hi_bf(X.y);
    };

    if (deg <= 16) {
        // ---- single-chunk fast path ----
        int e = beg + q;
        bool valid = q < deg;
        float av = valid ? att[e] : -3.4e38f;
        int tr = valid ? spair[e].y : 0;
        float m = av;
#pragma unroll
        for (int o = 1; o <= 8; o <<= 1) m = fmaxf(m, __shfl_xor(m, o, 64));
        float ev = valid ? __expf(av - m) : 0.f;
        ssum = ev;
        auto B = [&](int j) { body(__shfl(ev, qbase | j, 64), __shfl(tr, qbase | j, 64)); };
        int j = 0;
        for (; j + 4 <= deg; j += 4) { B(j); B(j + 1); B(j + 2); B(j + 3); }
        for (; j < deg; ++j) B(j);
    } else {
        // ---- general chunked path ----
        float m = -3.4e38f;
        for (int e = beg + q; e < end; e += 16) m = fmaxf(m, att[e]);
#pragma unroll
        for (int o = 1; o <= 8; o <<= 1) m = fmaxf(m, __shfl_xor(m, o, 64));

        for (int c = beg; c < end; c += 16) {
            int e = c + q;
            float ev = 0.f; int tr = 0;
            if (e < end) {
                ev = __expf(att[e] - m);
                tr = spair[e].y;
            }
            ssum += ev;
            int nc = min(16, end - c);
            auto B = [&](int j) { body(__shfl(ev, qbase | j, 64), __shfl(tr, qbase | j, 64)); };
            if (nc == 16) {
#pragma unroll 4
                for (int j = 0; j < 16; ++j) B(j);
            } else {
                int j = 0;
                for (; j + 4 <= nc; j += 4) { B(j); B(j + 1); B(j + 2); B(j + 3); }
                for (; j < nc; ++j) B(j);
            }
        }
    }
#pragma unroll
    for (int o = 1; o <= 8; o <<= 1) ssum += __shfl_xor(ssum, o, 64);

    float scale = (deg > 0) ? 1.0f / (ssum * (float)deg) : 0.f;
    float4 v = make_float4(acc4.x * scale, acc4.y * scale, acc4.z * scale, acc4.w * scale);
    float ss = v.x * v.x + v.y * v.y + v.z * v.z + v.w * v.w;
#pragma unroll
    for (int o = 1; o <= 8; o <<= 1) ss += __shfl_xor(ss, o, 64);
    float rinv = 1.0f / fmaxf(sqrtf(ss), 1e-12f);
    v.x *= rinv; v.y *= rinv; v.z *= rinv; v.w *= rinv;

    short2 c0 = cvt2(v.x, v.y), c1 = cvt2(v.z, v.w);
    ((short4*)aggNewBf)[(size_t)h * 16 + q] = make_short4(c0.x, c0.y, c1.x, c1.y);
    float4 kgv = ((float4*)kg)[(size_t)h * 16 + q];
    float4 ev2 = ((const float4*)ent)[(size_t)h * 16 + q];
    kgv.x += v.x + ev2.x; kgv.y += v.y + ev2.y;
    kgv.z += v.z + ev2.z; kgv.w += v.w + ev2.w;
    ((float4*)kg)[(size_t)h * 16 + q] = kgv;
}

extern "C" void kernel_launch(void* const* d_in, const int* in_sizes, int n_in,
                              void* d_out, int out_size, void* d_ws, size_t ws_size,
                              hipStream_t stream) {
    const float* ent  = (const float*)d_in[0];
    const float* eemb = (const float*)d_in[1];
    const float* qw   = (const float*)d_in[2];
    const float* kw   = (const float*)d_in[3];
    const int* eidx  = (const int*)d_in[4];
    const int* etype = (const int*)d_in[5];

    const int N = in_sizes[0] / EMB;
    const int R = in_sizes[1] / EMB;
    const int E = in_sizes[5];
    const int* head = eidx;
    const int* tail = eidx + E;

    float* kg = (float*)d_out;

    // workspace layout
    float* att   = (float*)d_ws;                 // E f32
    int2* spair  = (int2*)(att + E);             // E int2
    int* offsets = (int*)(spair + E);            // N+1
    int* deg     = offsets + (N + 1);            // N
    int* bcursor = deg + N;                      // N (only nbk used)
    int* bsum    = bcursor + N;                  // 1024
    uintptr_t pa = ((uintptr_t)(bsum + 1024) + 15) & ~(uintptr_t)15;
    short* aggbf_a = (short*)pa;                 // N*EMB bf16 (16-B aligned)
    short* aggbf_b = aggbf_a + (size_t)N * EMB;  // N*EMB bf16
    short* Qbf     = aggbf_b + (size_t)N * EMB;  // N*EMB bf16
    int2* tmp      = (int2*)Qbf;                 // E int2, aliases Qbf (pre-hop only)

    const int NT = 256;
    const int nb = (N + 1023) / 1024;
    const int nbk = (N + (1 << BSHIFT) - 1) >> BSHIFT;

    init_kernel<<<(N * EMB / 4 + NT - 1) / NT, NT, 0, stream>>>(
        (short4*)aggbf_a, (float4*)kg, (const float4*)ent, deg, N * EMB / 4, N);
    hist_kernel<<<(E + NT - 1) / NT, NT, 0, stream>>>(deg, head, E);
    scan_blocks<<<nb, NT, 0, stream>>>(deg, offsets, bsum, N);
    scan_sums<<<1, NT, 0, stream>>>(bsum, offsets, nb, N, E);
    scan_add<<<(N + NT - 1) / NT, NT, 0, stream>>>(offsets, bsum, bcursor, N);
    bucket_scatter<<<(E + CH - 1) / CH, NT, 0, stream>>>(head, tail, etype, bcursor, tmp, E, nbk);
    bucket_sort<<<nbk, NT, 0, stream>>>(offsets, tmp, spair, N);

    short* curbf = aggbf_a;
    short* nxtbf = aggbf_b;
    for (int hop = 0; hop < 2; ++hop) {
        qproj_mfma_kernel<<<1024, NT, 0, stream>>>(Qbf, curbf, qw, N);
        att_mfma_kernel<<<2048, NT, 0, stream>>>(att, curbf, Qbf, eemb, kw, spair, E);
        // 4 waves/block x 4 heads/wave = 16 heads/block
        head_agg_kernel<<<(N + 15) / 16, NT, 0, stream>>>(nxtbf, kg, att, curbf,
                                                          eemb, ent, offsets, spair, N, R);
        short* ts = curbf; curbf = nxtbf; nxtbf = ts;
    }
}